// Round 2
// baseline (131.215 us; speedup 1.0000x reference)
//
#include <hip/hip_runtime.h>

// Erosion2d: 3x3 windowed min, stride 1, pad with +huge (never selected since
// inputs are N(0,1) and reference pad is 1e9).
// Shapes: N=16, C=64, H=256, W=256 (fp32 in, fp32 out).
//
// Round 2: 8 rows/thread (halo 1.0625x), shuffle-based horizontal neighbors
// (no scalar edge loads; wave spans full 256-wide row), XCD-aware block
// swizzle so each plane's y-tiles share one XCD's L2 for halo rows.

#define HH 256
#define WW 256
#define PADV 1e30f

__device__ __forceinline__ float4 hmin_row_sh(const float* __restrict__ row,
                                              int x0, int lane) {
    float4 v = *reinterpret_cast<const float4*>(row + x0);
    float left  = __shfl_up(v.w, 1, 64);   // lane l gets lane l-1's v.w
    float right = __shfl_down(v.x, 1, 64); // lane l gets lane l+1's v.x
    if (lane == 0)  left  = PADV;          // x0==0   -> pad
    if (lane == 63) right = PADV;          // x0+4==W -> pad
    float4 h;
    h.x = fminf(left, fminf(v.x, v.y));
    h.y = fminf(v.x,  fminf(v.y, v.z));
    h.z = fminf(v.y,  fminf(v.z, v.w));
    h.w = fminf(v.z,  fminf(v.w, right));
    return h;
}

__global__ __launch_bounds__(256)
void erosion3x3_kernel(const float* __restrict__ in, float* __restrict__ out) {
    // 8192 blocks total: 1024 planes x 8 y-tiles (32 rows each).
    // Bijective XCD swizzle (nwg % 8 == 0): dispatch id -> original id such
    // that each XCD gets a contiguous chunk of original ids; consecutive
    // original ids (same plane, adjacent y-tiles) then share one XCD's L2.
    const int nwg  = 16 * 64 * 8;
    const int bid  = blockIdx.x;
    const int orig = (bid & 7) * (nwg >> 3) + (bid >> 3);

    const int plane = orig >> 3;      // n*64 + c
    const int ytile = orig & 7;       // 32-row tile within plane

    const int lane = threadIdx.x & 63;   // x-quad: x0 = 4*lane (wave = full row)
    const int ryt  = threadIdx.x >> 6;   // row-group 0..3 (8 rows each)

    const int y0 = ytile * 32 + ryt * 8;
    const int x0 = lane * 4;

    const float* __restrict__ base  = in  + (size_t)plane * (HH * WW);
    float*       __restrict__ obase = out + (size_t)plane * (HH * WW);

    const float4 pad4 = make_float4(PADV, PADV, PADV, PADV);

    float4 hm_prev = (y0 > 0) ? hmin_row_sh(base + (size_t)(y0 - 1) * WW, x0, lane)
                              : pad4;
    float4 hm_cur  = hmin_row_sh(base + (size_t)y0 * WW, x0, lane);

#pragma unroll
    for (int i = 0; i < 8; ++i) {
        const int yn = y0 + 1 + i;
        float4 hm_next = (yn < HH) ? hmin_row_sh(base + (size_t)yn * WW, x0, lane)
                                   : pad4;

        float4 o;
        o.x = fminf(hm_prev.x, fminf(hm_cur.x, hm_next.x));
        o.y = fminf(hm_prev.y, fminf(hm_cur.y, hm_next.y));
        o.z = fminf(hm_prev.z, fminf(hm_cur.z, hm_next.z));
        o.w = fminf(hm_prev.w, fminf(hm_cur.w, hm_next.w));

        *reinterpret_cast<float4*>(obase + (size_t)(y0 + i) * WW + x0) = o;

        hm_prev = hm_cur;
        hm_cur  = hm_next;
    }
}

extern "C" void kernel_launch(void* const* d_in, const int* in_sizes, int n_in,
                              void* d_out, int out_size, void* d_ws, size_t ws_size,
                              hipStream_t stream) {
    const float* x = (const float*)d_in[0];
    float* out = (float*)d_out;

    const int blocks = 16 * 64 * 8;   // planes * (256 rows / 32 rows per block)
    erosion3x3_kernel<<<blocks, 256, 0, stream>>>(x, out);
}

// Round 3
// 104.535 us; speedup vs baseline: 1.2552x; 1.2552x over previous
//
#include <hip/hip_runtime.h>

// Erosion2d: 3x3 windowed min, stride 1, pad with +huge (never selected since
// inputs are N(0,1) and reference pad is 1e9).
// Shapes: N=16, C=64, H=256, W=256 (fp32 in, fp32 out).
//
// Round 3: round-1 structure (4-row rolling window per thread, float4 row
// loads + 2 scalar edge loads, VMEM-only) with ONE change: 512-thread blocks
// covering 32 rows -> halo overfetch 1.0625x (was 1.125x).

#define HH 256
#define WW 256
#define PADV 1e30f

__device__ __forceinline__ float4 hmin_row(const float* __restrict__ row, int x0) {
    // x0 is a multiple of 4 in [0, 252]
    float4 v = *reinterpret_cast<const float4*>(row + x0);
    float left  = (x0 > 0)        ? row[x0 - 1] : PADV;
    float right = (x0 + 4 < WW)   ? row[x0 + 4] : PADV;
    float4 h;
    h.x = fminf(left, fminf(v.x, v.y));
    h.y = fminf(v.x,  fminf(v.y, v.z));
    h.z = fminf(v.y,  fminf(v.z, v.w));
    h.w = fminf(v.z,  fminf(v.w, right));
    return h;
}

__global__ __launch_bounds__(512)
void erosion3x3_kernel(const float* __restrict__ in, float* __restrict__ out) {
    // One thread computes a 4(rows) x 4(cols) output patch.
    // Block: 512 threads = 64 x-quads (full row of W=256) x 8 row-quads (32 rows).
    // Grid: planes(16*64=1024) * (256/32 = 8 row-tiles) = 8192 blocks.
    const int tid  = threadIdx.x;
    const int xq   = tid & 63;        // x-quad index: x0 = 4*xq
    const int ryt  = tid >> 6;        // row-quad within block: 0..7
    const int b    = blockIdx.x;
    const int plane   = b >> 3;       // 0..1023  (n*64 + c)
    const int ytileBl = b & 7;        // 32-row tile within plane

    const int y0 = ytileBl * 32 + ryt * 4;
    const int x0 = xq * 4;

    const float* __restrict__ base  = in  + (size_t)plane * (HH * WW);
    float*       __restrict__ obase = out + (size_t)plane * (HH * WW);

    float4 hm_prev, hm_cur, hm_next;

    if (y0 > 0) hm_prev = hmin_row(base + (size_t)(y0 - 1) * WW, x0);
    else        hm_prev = make_float4(PADV, PADV, PADV, PADV);

    hm_cur = hmin_row(base + (size_t)y0 * WW, x0);

#pragma unroll
    for (int i = 0; i < 4; ++i) {
        const int yn = y0 + 1 + i;
        if (yn < HH) hm_next = hmin_row(base + (size_t)yn * WW, x0);
        else         hm_next = make_float4(PADV, PADV, PADV, PADV);

        float4 o;
        o.x = fminf(hm_prev.x, fminf(hm_cur.x, hm_next.x));
        o.y = fminf(hm_prev.y, fminf(hm_cur.y, hm_next.y));
        o.z = fminf(hm_prev.z, fminf(hm_cur.z, hm_next.z));
        o.w = fminf(hm_prev.w, fminf(hm_cur.w, hm_next.w));

        *reinterpret_cast<float4*>(obase + (size_t)(y0 + i) * WW + x0) = o;

        hm_prev = hm_cur;
        hm_cur  = hm_next;
    }
}

extern "C" void kernel_launch(void* const* d_in, const int* in_sizes, int n_in,
                              void* d_out, int out_size, void* d_ws, size_t ws_size,
                              hipStream_t stream) {
    const float* x = (const float*)d_in[0];
    float* out = (float*)d_out;

    // 16*64 planes, each 256x256; 32 rows per 512-thread block.
    const int blocks = 16 * 64 * (HH / 32);
    erosion3x3_kernel<<<blocks, 512, 0, stream>>>(x, out);
}

// Round 5
// 85.138 us; speedup vs baseline: 1.5412x; 1.2278x over previous
//
#include <hip/hip_runtime.h>

// Erosion2d: 3x3 windowed min, stride 1, pad with +huge (never selected since
// inputs are N(0,1) and reference pad is 1e9).
// Shapes: N=16, C=64, H=256, W=256 (fp32 in, fp32 out).
//
// Round 5: R3 structure (4-row rolling window, float4 + 2 scalar edge loads,
// 512-thread blocks / 32 rows) + nontemporal output stores (via native clang
// vector type — HIP_vector_type isn't accepted by the builtin).

#define HH 256
#define WW 256
#define PADV 1e30f

typedef float v4f __attribute__((ext_vector_type(4)));

__device__ __forceinline__ float4 hmin_row(const float* __restrict__ row, int x0) {
    // x0 is a multiple of 4 in [0, 252]
    float4 v = *reinterpret_cast<const float4*>(row + x0);
    float left  = (x0 > 0)        ? row[x0 - 1] : PADV;
    float right = (x0 + 4 < WW)   ? row[x0 + 4] : PADV;
    float4 h;
    h.x = fminf(left, fminf(v.x, v.y));
    h.y = fminf(v.x,  fminf(v.y, v.z));
    h.z = fminf(v.y,  fminf(v.z, v.w));
    h.w = fminf(v.z,  fminf(v.w, right));
    return h;
}

__global__ __launch_bounds__(512)
void erosion3x3_kernel(const float* __restrict__ in, float* __restrict__ out) {
    // One thread computes a 4(rows) x 4(cols) output patch.
    // Block: 512 threads = 64 x-quads (full row of W=256) x 8 row-quads (32 rows).
    // Grid: planes(16*64=1024) * (256/32 = 8 row-tiles) = 8192 blocks.
    const int tid  = threadIdx.x;
    const int xq   = tid & 63;        // x-quad index: x0 = 4*xq
    const int ryt  = tid >> 6;        // row-quad within block: 0..7
    const int b    = blockIdx.x;
    const int plane   = b >> 3;       // 0..1023  (n*64 + c)
    const int ytileBl = b & 7;        // 32-row tile within plane

    const int y0 = ytileBl * 32 + ryt * 4;
    const int x0 = xq * 4;

    const float* __restrict__ base  = in  + (size_t)plane * (HH * WW);
    float*       __restrict__ obase = out + (size_t)plane * (HH * WW);

    float4 hm_prev, hm_cur, hm_next;

    if (y0 > 0) hm_prev = hmin_row(base + (size_t)(y0 - 1) * WW, x0);
    else        hm_prev = make_float4(PADV, PADV, PADV, PADV);

    hm_cur = hmin_row(base + (size_t)y0 * WW, x0);

#pragma unroll
    for (int i = 0; i < 4; ++i) {
        const int yn = y0 + 1 + i;
        if (yn < HH) hm_next = hmin_row(base + (size_t)yn * WW, x0);
        else         hm_next = make_float4(PADV, PADV, PADV, PADV);

        v4f o;
        o.x = fminf(hm_prev.x, fminf(hm_cur.x, hm_next.x));
        o.y = fminf(hm_prev.y, fminf(hm_cur.y, hm_next.y));
        o.z = fminf(hm_prev.z, fminf(hm_cur.z, hm_next.z));
        o.w = fminf(hm_prev.w, fminf(hm_cur.w, hm_next.w));

        // Nontemporal: output is write-once, never re-read -> don't allocate
        // in L2/L3, keep those for the input halo reuse.
        __builtin_nontemporal_store(o, reinterpret_cast<v4f*>(
            obase + (size_t)(y0 + i) * WW + x0));

        hm_prev = hm_cur;
        hm_cur  = hm_next;
    }
}

extern "C" void kernel_launch(void* const* d_in, const int* in_sizes, int n_in,
                              void* d_out, int out_size, void* d_ws, size_t ws_size,
                              hipStream_t stream) {
    const float* x = (const float*)d_in[0];
    float* out = (float*)d_out;

    // 16*64 planes, each 256x256; 32 rows per 512-thread block.
    const int blocks = 16 * 64 * (HH / 32);
    erosion3x3_kernel<<<blocks, 512, 0, stream>>>(x, out);
}